// Round 8
// baseline (218.384 us; speedup 1.0000x reference)
//
#include <hip/hip_runtime.h>

// Problem constants: B=4, C=3, H=512, W=960, K2=16 -> K=4
#define BB 4
#define CC 3
#define HH 512
#define WW 960
#define HW (HH * WW)

// 2D tiling: 64x4 pixels per 256-thread block (round-2 best structure)
#define TW 64
#define TH 4
#define NTX (WW / TW)          // 15
#define NTY (HH / TH)          // 128
#define NBLK (BB * NTX * NTY)  // 7680

// Staged input tile: rows y0-5 .. y0+10 (16), cols x0-8 .. x0+71 (80), 3 ch.
// Layout [s][ch][t], UNPADDED stride 80 -> linear in load index, so interior
// staging can use global_load_lds (wave-uniform base + lane*16B).
#define ROWS 16
#define COLS 80
#define RSTRIDE (CC * COLS)             // 240 floats per staged row
#define LDS_IN_FLOATS (ROWS * RSTRIDE)  // 3840 floats = 15360 B

// Filter/flow staged via DMA (round-7 win: VMEM wave-instrs ~99 -> ~45).
// Layout [k][px]: post-barrier read lds_f[k*256+tid] is conflict-free.
#define LDS_F_FLOATS (16 * 256)         // 16384 B
#define LDS_FL_FLOATS (2 * 256)         // 2048 B

typedef __attribute__((address_space(1))) const unsigned int gu32;
typedef __attribute__((address_space(3))) unsigned int lu32;

__global__ __launch_bounds__(256)
void filter_interp_kernel(const float* __restrict__ inp,
                          const float* __restrict__ flow,
                          const float* __restrict__ filt,
                          float* __restrict__ out) {
    __shared__ float lds[LDS_IN_FLOATS];
    __shared__ float lds_f[LDS_F_FLOATS];
    __shared__ float lds_fl[LDS_FL_FLOATS];

    // Bijective XCD-aware swizzle (NBLK % 8 == 0): ty-fastest -> each XCD
    // works a contiguous vertical strip; input slice fits its L2.
    const int bid = blockIdx.x;
    const int swz = (bid & 7) * (NBLK / 8) + (bid >> 3);
    const int b   = swz / (NTX * NTY);
    const int rr  = swz - b * (NTX * NTY);
    const int tx  = rr / NTY;
    const int ty  = rr - tx * NTY;
    const int x0  = tx * TW;
    const int y0  = ty * TH;

    const int tid  = threadIdx.x;
    const int wave = tid >> 6;
    const float* ibase = inp  + (size_t)b * CC * HW;
    const float* fbase = filt + (size_t)b * 16 * HW;

    // ---- Stage input tile into LDS ----
    if (tx > 0 && tx < NTX - 1) {
        // Interior in x: async DMA straight to LDS, no VGPR round-trip.
#pragma unroll
        for (int e = 0; e < 4; ++e) {
            const int idx = e * 256 + tid;
            if (idx < ROWS * CC * (COLS / 4)) {          // 960 float4s
                const int s  = idx / 60;                 // CC*(COLS/4)
                const int r2 = idx - s * 60;
                const int ch = r2 / 20;                  // COLS/4
                const int t4 = r2 - ch * 20;
                const int grow = min(max(y0 - 5 + s, 0), HH - 1);
                const float* src = ibase + (size_t)ch * HW +
                                   (size_t)grow * WW + (x0 - 8 + t4 * 4);
                lu32* dst = (lu32*)(void*)&lds[(e * 256 + wave * 64) * 4];
                __builtin_amdgcn_global_load_lds((gu32*)(const void*)src,
                                                 dst, 16, 0, 0);
            }
        }
    } else {
        // x-edge tile: scalar loads with per-column clamp.
#pragma unroll
        for (int e = 0; e < 15; ++e) {
            const int idx = e * 256 + tid;               // exactly 3840 total
            const int s  = idx / RSTRIDE;
            const int r2 = idx - s * RSTRIDE;
            const int ch = r2 / COLS;
            const int t  = r2 - ch * COLS;
            const int grow = min(max(y0 - 5 + s, 0), HH - 1);
            const int gcol = min(max(x0 - 8 + t, 0), WW - 1);
            lds[idx] = ibase[(size_t)ch * HW + (size_t)grow * WW + gcol];
        }
    }

    // ---- Stage filter (16 DMA instrs/block) and flow (2) ----
    // Tap k's tile slab filt[b][k][y0..y0+3][x0..x0+63] = 1KB: lane l loads
    // 16B at (row y0 + l/16, col x0 + (l%16)*4); dest linear [k][row][col].
    const int l    = tid & 63;
    const int frow = l >> 4;           // 0..3
    const int fcol = (l & 15) << 2;    // 0..60
    const float* fsrc = fbase + (size_t)(y0 + frow) * WW + (x0 + fcol);
#pragma unroll
    for (int q = 0; q < 4; ++q) {
        const int k = (wave << 2) + q;                 // wave w -> taps 4w..4w+3
        const float* src = fsrc + (size_t)k * HW;
        lu32* dst = (lu32*)(void*)&lds_f[k << 8];
        __builtin_amdgcn_global_load_lds((gu32*)(const void*)src, dst, 16, 0, 0);
    }
    if (wave < 2) {                                    // wave-uniform branch
        const float* src = flow + (size_t)(b * 2 + wave) * HW +
                           (size_t)(y0 + frow) * WW + (x0 + fcol);
        lu32* dst = (lu32*)(void*)&lds_fl[wave << 8];
        __builtin_amdgcn_global_load_lds((gu32*)(const void*)src, dst, 16, 0, 0);
    }

    __syncthreads();   // vmcnt(0) here drains all DMA

    const int lx = tid & (TW - 1);
    const int wy = tid >> 6;
    const int x  = x0 + lx;
    const int y  = y0 + wy;
    const int rem = y * WW + x;

    // Flow + filter from LDS (conflict-free: lanes consecutive).
    const float fx = lds_fl[tid];
    const float fy = lds_fl[256 + tid];

    float f[16];
#pragma unroll
    for (int k = 0; k < 16; ++k) f[k] = lds_f[(k << 8) + tid];

    const float x2 = (float)x + fx;
    const float y2 = (float)y + fy;

    const bool valid = (x2 >= 0.0f) && (x2 <= (float)(WW - 1)) &&
                       (y2 >= 0.0f) && (y2 <= (float)(HH - 1)) &&
                       (fabsf(fx) < (float)WW * 0.5f) &&
                       (fabsf(fy) < (float)HH * 0.5f);

    float acc0 = 0.0f, acc1 = 0.0f, acc2 = 0.0f;

    if (valid) {
        const int ix = (int)floorf(x2);
        const int iy = (int)floorf(y2);
        const float alpha = x2 - (float)ix;
        const float beta  = y2 - (float)iy;

        const float wTL = (1.0f - alpha) * (1.0f - beta);
        const float wTR = alpha * (1.0f - beta);
        const float wBL = (1.0f - alpha) * beta;
        const float wBR = alpha * beta;

        // Fold 16 taps x 4 bilinear weights into 5x5 (channel-independent).
        float Wm[5][5];
#pragma unroll
        for (int j = 0; j < 5; ++j)
#pragma unroll
            for (int i = 0; i < 5; ++i) Wm[j][i] = 0.0f;
#pragma unroll
        for (int dj = 0; dj < 4; ++dj) {
#pragma unroll
            for (int di = 0; di < 4; ++di) {
                const float fv = f[dj * 4 + di];
                Wm[dj][di]         += fv * wTL;
                Wm[dj][di + 1]     += fv * wTR;
                Wm[dj + 1][di]     += fv * wBL;
                Wm[dj + 1][di + 1] += fv * wBR;
            }
        }

        const int ixL0 = ix - 1;
        const int iyT0 = iy - 1;
        const int cs = ixL0 - (x0 - 8);   // col slot of window start
        const int rs = iyT0 - (y0 - 5);   // row slot of window start

        if ((unsigned)rs <= (unsigned)(ROWS - 5) &&
            (unsigned)cs <= (unsigned)(COLS - 5)) {
            // Fast path: BROADCAST-FRIENDLY b128 gather. Window aligned down
            // to 4-float base e0 = cs & ~3 (cs <= 75 -> e0+7 <= 79, in range;
            // 16B-aligned since RSTRIDE/COLS/e0 are multiples of 4). Runs of
            // ~4 consecutive lanes share the same 16B slot -> same-address
            // broadcast (free), ~17 distinct slots per wave-read instead of
            // 64 conflicted b64s. 30 reads/px instead of 45.
            const int o  = cs & 3;
            const int e0 = cs - o;
            const float* lbase = lds + rs * RSTRIDE + e0;

            // Barrel-shift each 5-wide weight row into an 8-wide row:
            // We[j][i] = Wm[j][i-o] for i-o in [0,4], else 0. (r0-verified.)
            const bool s2 = (o & 2) != 0;
            const bool s1 = (o & 1) != 0;
            float We[5][8];
#pragma unroll
            for (int j = 0; j < 5; ++j) {
                float t[8];
#pragma unroll
                for (int i = 0; i < 8; ++i) t[i] = (i < 5) ? Wm[j][i] : 0.0f;
                float u[8];
#pragma unroll
                for (int i = 0; i < 8; ++i)
                    u[i] = s2 ? ((i >= 2) ? t[i - 2] : 0.0f) : t[i];
#pragma unroll
                for (int i = 0; i < 8; ++i)
                    We[j][i] = s1 ? ((i >= 1) ? u[i - 1] : 0.0f) : u[i];
            }

            float acc[3] = {0.0f, 0.0f, 0.0f};
#pragma unroll
            for (int j = 0; j < 5; ++j) {
                const float* lr = lbase + j * RSTRIDE;
#pragma unroll
                for (int ch = 0; ch < 3; ++ch) {
                    const float4 p0 = *(const float4*)(lr + ch * COLS);
                    const float4 p1 = *(const float4*)(lr + ch * COLS + 4);
                    float a = acc[ch];
                    a += p0.x * We[j][0];
                    a += p0.y * We[j][1];
                    a += p0.z * We[j][2];
                    a += p0.w * We[j][3];
                    a += p1.x * We[j][4];
                    a += p1.y * We[j][5];
                    a += p1.z * We[j][6];
                    a += p1.w * We[j][7];
                    acc[ch] = a;
                }
            }
            acc0 = acc[0]; acc1 = acc[1]; acc2 = acc[2];
        } else {
            // Rare fallback (|flow| beyond tile margin but still valid):
            // scalar clamped global gathers, same math as verified slow path.
            int R[5], S[5];
#pragma unroll
            for (int j = 0; j < 5; ++j) R[j] = min(max(iyT0 + j, 0), HH - 1);
#pragma unroll
            for (int i = 0; i < 5; ++i) S[i] = min(max(ixL0 + i, 0), WW - 1);
#pragma unroll
            for (int j = 0; j < 5; ++j) {
                const float* r0 = ibase + (size_t)R[j] * WW;
#pragma unroll
                for (int i = 0; i < 5; ++i) {
                    const float w = Wm[j][i];
                    const size_t oidx = (size_t)S[i];
                    acc0 += r0[oidx] * w;
                    acc1 += r0[HW + oidx] * w;
                    acc2 += r0[2 * (size_t)HW + oidx] * w;
                }
            }
        }
    }

    const int outbase = b * CC * HW + rem;
    out[outbase]          = acc0;
    out[outbase + HW]     = acc1;
    out[outbase + 2 * HW] = acc2;
}

extern "C" void kernel_launch(void* const* d_in, const int* in_sizes, int n_in,
                              void* d_out, int out_size, void* d_ws, size_t ws_size,
                              hipStream_t stream) {
    const float* teninput  = (const float*)d_in[0];
    const float* tenflow   = (const float*)d_in[1];
    const float* tenfilter = (const float*)d_in[2];
    float* out = (float*)d_out;

    filter_interp_kernel<<<NBLK, 256, 0, stream>>>(teninput, tenflow, tenfilter, out);
}